// Round 6
// baseline (929.721 us; speedup 1.0000x reference)
//
#include <hip/hip_runtime.h>
#include <hip/hip_bf16.h>
#include <math.h>

#define CDIM 192
#define NTOK 131072   /* B*H*W = 2*256*256 */
#define HD 24
#define NHEADS 8
#define NTC 65536     /* tokens per attention chunk (one batch) */

typedef __attribute__((ext_vector_type(4))) float floatx4;
typedef __attribute__((ext_vector_type(8))) short bf16x8;
typedef __attribute__((ext_vector_type(4))) unsigned int uintx4;

static __device__ __forceinline__ float bf2f(__hip_bfloat16 h) { return __bfloat162float(h); }
static __device__ __forceinline__ __hip_bfloat16 f2bf(float f) { return __float2bfloat16(f); }
static __device__ __forceinline__ float s2f(short s) {
  union { unsigned u; float f; } c; c.u = ((unsigned)(unsigned short)s) << 16; return c.f;
}
static __device__ __forceinline__ short f2s(float f) {
  __hip_bfloat16 h = __float2bfloat16(f);
  union { __hip_bfloat16 h; short s; } c; c.h = h; return c.s;
}
static __device__ __forceinline__ void load_lds16(const void* g, void* l) {
  __builtin_amdgcn_global_load_lds(
      (const __attribute__((address_space(1))) void*)g,
      (__attribute__((address_space(3))) void*)l, 16, 0, 0);
}

// ---------------- KC: f32 -> bf16 convert ----------------
__global__ __launch_bounds__(256) void kcvt(
    const float* __restrict__ in, __hip_bfloat16* __restrict__ out, int n) {
  int i = blockIdx.x * 256 + threadIdx.x;
  if (i < n) out[i] = f2bf(in[i]);
}

// ---------------- K0a: pad pout_w (192,510) f32 -> (192,512) bf16 ----------------
__global__ __launch_bounds__(256) void k0_padpout(
    const float* __restrict__ w, __hip_bfloat16* __restrict__ o) {
  int idx = blockIdx.x * 256 + threadIdx.x;   // 192*512
  int n = idx >> 9, k = idx & 511;
  o[idx] = (k < 510) ? f2bf(w[n * 510 + k]) : f2bf(0.f);
}

// ---------------- K0b: pad pin_w (1020,192) f32 -> (1024,192) bf16, scaled by nw ----
__global__ __launch_bounds__(256) void k0_padpin(
    const float* __restrict__ w, const float* __restrict__ nw,
    __hip_bfloat16* __restrict__ o) {
  int idx = blockIdx.x * 256 + threadIdx.x;   // 1024*192
  int n = idx / 192, k = idx % 192;
  int src = (n < 510) ? n : ((n >= 512 && n < 1022) ? n - 2 : -1);
  o[idx] = (src >= 0) ? f2bf(w[src * 192 + k] * nw[k]) : f2bf(0.f);
}

// ---------------- K0s: LN2-fold vectors S[n]=sum(W*nw), T[n]=sum(W*nb) ----------------
__global__ __launch_bounds__(256) void k0_st(
    const float* __restrict__ w, const float* __restrict__ nw,
    const float* __restrict__ nb, float* __restrict__ S, float* __restrict__ T) {
  int n = blockIdx.x * 256 + threadIdx.x;     // [0,1024)
  int src = (n < 510) ? n : ((n >= 512 && n < 1022) ? n - 2 : -1);
  float s = 0.f, t = 0.f;
  if (src >= 0)
    for (int c = 0; c < 192; ++c) {
      float v = w[src * 192 + c];
      s += v * nw[c]; t += v * nb[c];
    }
  S[n] = s; T[n] = t;
}

// ---------------- K0c: transpose dw_w (1020,9) f32 -> tap-major bf16 WA[9][512], WG[9][512] ---
__global__ __launch_bounds__(256) void k0_wtap(
    const float* __restrict__ wdw, __hip_bfloat16* __restrict__ wa,
    __hip_bfloat16* __restrict__ wg) {
  int idx = blockIdx.x * 256 + threadIdx.x;   // 9*512
  if (idx >= 9 * 512) return;
  int tap = idx >> 9, c = idx & 511;
  wa[idx] = (c < 510) ? f2bf(wdw[c * 9 + tap]) : f2bf(0.f);
  wg[idx] = (c < 510) ? f2bf(wdw[(c + 510) * 9 + tap]) : f2bf(0.f);
}

// ---------------- K1: LN1 + cyclic shift, shifted-raster order (f32 in, bf16 out) --------
// Coalesced float4 reads -> LDS transpose -> thread=(token,24-ch group): local sum over
// 24 ch + 3-level shfl butterfly over 8 lanes (all 32 tokens reduce in parallel),
// normalize+pack in-register, 48B/thread stores (per-wave addresses = tid*48, coalesced).
__global__ __launch_bounds__(256) void k1_ln_raster(
    const float* __restrict__ x,
    const float* __restrict__ w,
    const float* __restrict__ bsh,
    __hip_bfloat16* __restrict__ out) {
  __shared__ float xs[32][193];
  __shared__ float wls[192], bls[192];
  int bid = blockIdx.x;
  int b = bid >> 11, si = (bid >> 3) & 255, sj0 = (bid & 7) << 5;
  int i = (si + 4) & 255;                     // unshifted source row
  int tid = threadIdx.x;
  int lane = tid & 63, wv = tid >> 6;
  if (tid < 192) { wls[tid] = w[tid]; bls[tid] = bsh[tid]; }
  int p0 = (lane & 7) << 2;
  int cb = wv * 8 + (lane >> 3);
  int j4 = (sj0 + p0 + 4) & 255;              // wrap-aligned source column
  long pbase = ((long)(b * CDIM + cb) << 16) + (i << 8) + j4;
  #pragma unroll
  for (int co = 0; co < 6; ++co) {
    floatx4 v = *(const floatx4*)(x + pbase + ((long)co << 21));
    int c = co * 32 + cb;
    xs[p0 + 0][c] = v[0];
    xs[p0 + 1][c] = v[1];
    xs[p0 + 2][c] = v[2];
    xs[p0 + 3][c] = v[3];
  }
  __syncthreads();
  int p = tid >> 3, q = tid & 7, c0 = q * 24;
  float v[24], s = 0.f, sq = 0.f;
  #pragma unroll
  for (int e = 0; e < 24; ++e) {
    float t = xs[p][c0 + e]; v[e] = t; s += t; sq += t * t;
  }
  #pragma unroll
  for (int off = 1; off < 8; off <<= 1) { s += __shfl_xor(s, off); sq += __shfl_xor(sq, off); }
  float mean = s * (1.0f / 192.0f);
  float var  = sq * (1.0f / 192.0f) - mean * mean;
  float rstd = rsqrtf(var + 1e-5f);
  unsigned pk[12];
  #pragma unroll
  for (int e = 0; e < 12; ++e) {
    unsigned lo = (unsigned short)f2s((v[2*e  ] - mean) * rstd * wls[c0 + 2*e  ] + bls[c0 + 2*e  ]);
    unsigned hi = (unsigned short)f2s((v[2*e+1] - mean) * rstd * wls[c0 + 2*e+1] + bls[c0 + 2*e+1]);
    pk[e] = lo | (hi << 16);
  }
  long tok0 = ((long)b << 16) + (si << 8) + sj0;
  char* gout = (char*)out + (tok0 + p) * 384 + q * 48;
  *(uintx4*)(gout     ) = (uintx4){pk[0], pk[1], pk[2], pk[3]};
  *(uintx4*)(gout + 16) = (uintx4){pk[4], pk[5], pk[6], pk[7]};
  *(uintx4*)(gout + 32) = (uintx4){pk[8], pk[9], pk[10], pk[11]};
}

// ---------------- LDS-staged MFMA GEMM: C(M,N) = A(M,K)*B(N,K)^T ----------------
template <int WM, int WN, int EPI>
__global__ __launch_bounds__(256) void gemm_lds(
    const __hip_bfloat16* __restrict__ A,
    const __hip_bfloat16* __restrict__ B,
    const float* __restrict__ bias,
    __hip_bfloat16* __restrict__ C,
    int K, int lda, int ldb, int ldc) {
  constexpr int BM = 32 * WM, BN = 32 * WN;
  __shared__ __hip_bfloat16 As[BM * 32];
  __shared__ __hip_bfloat16 Bs[BN * 32];
  int t = threadIdx.x;
  int wave = t >> 6, lane = t & 63;
  int wm = wave >> 1, wn = wave & 1;
  int r16 = lane & 15, quad = lane >> 4;
  long m0 = (long)blockIdx.y * BM;
  long n0 = (long)blockIdx.x * BN;
  int srow = t >> 2, scol = (t & 3) << 3;
  floatx4 acc[WM][WN];
  for (int i = 0; i < WM; ++i)
    for (int j = 0; j < WN; ++j)
      acc[i][j] = (floatx4){0.f, 0.f, 0.f, 0.f};
  for (int k0 = 0; k0 < K; k0 += 32) {
    __syncthreads();
    for (int p = 0; p < WM / 2; ++p)
      load_lds16(A + (m0 + srow + p * 64) * lda + k0 + scol,
                 (char*)As + t * 16 + p * 4096);
    for (int p = 0; p < WN / 2; ++p)
      load_lds16(B + (n0 + srow + p * 64) * ldb + k0 + scol,
                 (char*)Bs + t * 16 + p * 4096);
    __syncthreads();
    bf16x8 af[WM], bf[WN];
    for (int i = 0; i < WM; ++i)
      af[i] = *(const bf16x8*)&As[(wm * 16 * WM + i * 16 + r16) * 32 + quad * 8];
    for (int j = 0; j < WN; ++j)
      bf[j] = *(const bf16x8*)&Bs[(wn * 16 * WN + j * 16 + r16) * 32 + quad * 8];
    for (int i = 0; i < WM; ++i)
      for (int j = 0; j < WN; ++j)
        acc[i][j] = __builtin_amdgcn_mfma_f32_16x16x32_bf16(af[i], bf[j], acc[i][j], 0, 0, 0);
  }
  for (int i = 0; i < WM; ++i)
    for (int j = 0; j < WN; ++j) {
      int col = n0 + wn * 16 * WN + j * 16 + r16;
      float badd = (EPI == 1) ? bias[col] : 0.f;
      for (int r = 0; r < 4; ++r) {
        long row = m0 + wm * 16 * WM + i * 16 + quad * 4 + r;
        C[row * ldc + col] = f2bf(acc[i][j][r] + badd);
      }
    }
}

// ---------------- qkv GEMM with padded head-plane scatter epilogue ----------------
// C planes: [sel(q/k/v)][head][tok][32] (dims 24-31 unwritten; k3 zero-masks them
// on BOTH the K side (LDS zeros) and the Q side (quad==3 fragment zeroed)).
__global__ __launch_bounds__(256) void gemm_qkv(
    const __hip_bfloat16* __restrict__ A,    // (NTC,192) ln1 chunk
    const __hip_bfloat16* __restrict__ B,    // qkv_w bf16 (576,192)
    __hip_bfloat16* __restrict__ C) {
  constexpr int WM = 4, WN = 2, BM = 128, BN = 64;
  __shared__ __hip_bfloat16 As[BM * 32];
  __shared__ __hip_bfloat16 Bs[BN * 32];
  int t = threadIdx.x;
  int wave = t >> 6, lane = t & 63;
  int wm = wave >> 1, wn = wave & 1;
  int r16 = lane & 15, quad = lane >> 4;
  long m0 = (long)blockIdx.y * BM;
  int n0 = blockIdx.x * BN;
  int srow = t >> 2, scol = (t & 3) << 3;
  floatx4 acc[WM][WN];
  for (int i = 0; i < WM; ++i)
    for (int j = 0; j < WN; ++j)
      acc[i][j] = (floatx4){0.f, 0.f, 0.f, 0.f};
  for (int k0 = 0; k0 < 192; k0 += 32) {
    __syncthreads();
    for (int p = 0; p < 2; ++p)
      load_lds16(A + (m0 + srow + p * 64) * 192 + k0 + scol,
                 (char*)As + t * 16 + p * 4096);
    load_lds16(B + (n0 + srow) * 192 + k0 + scol, (char*)Bs + t * 16);
    __syncthreads();
    bf16x8 af[WM], bf[WN];
    for (int i = 0; i < WM; ++i)
      af[i] = *(const bf16x8*)&As[(wm * 64 + i * 16 + r16) * 32 + quad * 8];
    for (int j = 0; j < WN; ++j)
      bf[j] = *(const bf16x8*)&Bs[(wn * 32 + j * 16 + r16) * 32 + quad * 8];
    for (int i = 0; i < WM; ++i)
      for (int j = 0; j < WN; ++j)
        acc[i][j] = __builtin_amdgcn_mfma_f32_16x16x32_bf16(af[i], bf[j], acc[i][j], 0, 0, 0);
  }
  for (int i = 0; i < WM; ++i)
    for (int j = 0; j < WN; ++j) {
      int col = n0 + wn * 32 + j * 16 + r16;   // [0,576)
      int sel = col / 192;
      int cm = col - sel * 192;
      int h = (cm * 683) >> 14;                // cm/24
      int d = cm - h * 24;
      long cb = (long)sel * (NTC * 256) + ((long)h << 21) + d;   // h*NTC*32
      for (int r = 0; r < 4; ++r) {
        long row = m0 + wm * 64 + i * 16 + quad * 4 + r;
        C[cb + (row << 5)] = f2bf(acc[i][j][r]);
      }
    }
}

// ---------------- pin GEMM with fused LN2 (A = x2 raw; epilogue applies LN fold) -----
__global__ __launch_bounds__(256) void gemm_pin(
    const __hip_bfloat16* __restrict__ x2,   // (NTOK,192) token-major
    const __hip_bfloat16* __restrict__ B,    // (1024,192) nw-scaled padded pin_w
    const float* __restrict__ stats,         // (NTOK,2)
    const float* __restrict__ Sv,
    const float* __restrict__ Tv,
    __hip_bfloat16* __restrict__ C,          // (16896,1024)
    int bb, int r0) {
  constexpr int WM = 4, WN = 4, BM = 128, BN = 128;
  __shared__ __hip_bfloat16 As[BM * 32];
  __shared__ __hip_bfloat16 Bs[BN * 32];
  int t = threadIdx.x;
  int wave = t >> 6, lane = t & 63;
  int wm = wave >> 1, wn = wave & 1;
  int r16 = lane & 15, quad = lane >> 4;
  int m0 = blockIdx.y * BM;
  int n0 = blockIdx.x * BN;
  int srow = t >> 2, scol = (t & 3) << 3;
  floatx4 acc[WM][WN];
  for (int i = 0; i < WM; ++i)
    for (int j = 0; j < WN; ++j)
      acc[i][j] = (floatx4){0.f, 0.f, 0.f, 0.f};
  for (int k0 = 0; k0 < 192; k0 += 32) {
    __syncthreads();
    for (int p = 0; p < 2; ++p) {
      int rr = m0 + srow + p * 64;
      int il = rr >> 8, jj = rr & 255;
      int gi = r0 - 1 + il; gi = gi < 0 ? 0 : (gi > 255 ? 255 : gi);
      long tok = ((long)bb << 16) + (gi << 8) + jj;
      load_lds16(x2 + tok * 192 + k0 + scol, (char*)As + t * 16 + p * 4096);
    }
    for (int p = 0; p < 2; ++p)
      load_lds16(B + (n0 + srow + p * 64) * 192 + k0 + scol,
                 (char*)Bs + t * 16 + p * 4096);
    __syncthreads();
    bf16x8 af[WM], bf[WN];
    for (int i = 0; i < WM; ++i)
      af[i] = *(const bf16x8*)&As[(wm * 64 + i * 16 + r16) * 32 + quad * 8];
    for (int j = 0; j < WN; ++j)
      bf[j] = *(const bf16x8*)&Bs[(wn * 64 + j * 16 + r16) * 32 + quad * 8];
    for (int i = 0; i < WM; ++i)
      for (int j = 0; j < WN; ++j)
        acc[i][j] = __builtin_amdgcn_mfma_f32_16x16x32_bf16(af[i], bf[j], acc[i][j], 0, 0, 0);
  }
  for (int i = 0; i < WM; ++i) {
    float mr[4], rsd[4];
    #pragma unroll
    for (int r = 0; r < 4; ++r) {
      int row = m0 + wm * 64 + i * 16 + quad * 4 + r;
      int il = row >> 8, jj = row & 255;
      int gi = r0 - 1 + il; gi = gi < 0 ? 0 : (gi > 255 ? 255 : gi);
      long tok = ((long)bb << 16) + (gi << 8) + jj;
      mr[r] = stats[2 * tok]; rsd[r] = stats[2 * tok + 1];
    }
    for (int j = 0; j < WN; ++j) {
      int col = n0 + wn * 64 + j * 16 + r16;
      float sv = Sv[col], tv = Tv[col];
      for (int r = 0; r < 4; ++r) {
        int row = m0 + wm * 64 + i * 16 + quad * 4 + r;
        C[(long)row * 1024 + col] = f2bf(acc[i][j][r] * rsd[r] - mr[r] * rsd[r] * sv + tv);
      }
    }
  }
}

// ---------------- pout GEMM (transposed output) + residual + coalesced f32 store ----
__global__ __launch_bounds__(256) void gemm_pout(
    const __hip_bfloat16* __restrict__ A,    // padded pout_w (192,512)
    const __hip_bfloat16* __restrict__ B,    // gated chunk (16384,512)
    const __hip_bfloat16* __restrict__ x2,
    float* __restrict__ out,
    int b, int r0) {
  constexpr int WM = 2, WN = 4, BM = 64, BN = 128;
  __shared__ __hip_bfloat16 As[BM * 32];
  __shared__ __hip_bfloat16 Bs[BN * 32];
  int t = threadIdx.x;
  int wave = t >> 6, lane = t & 63;
  int wm = wave >> 1, wn = wave & 1;
  int r16 = lane & 15, quad = lane >> 4;
  long m0 = (long)blockIdx.y * BM;
  long n0 = (long)blockIdx.x * BN;
  int srow = t >> 2, scol = (t & 3) << 3;
  floatx4 acc[WM][WN];
  for (int i = 0; i < WM; ++i)
    for (int j = 0; j < WN; ++j)
      acc[i][j] = (floatx4){0.f, 0.f, 0.f, 0.f};
  for (int k0 = 0; k0 < 512; k0 += 32) {
    __syncthreads();
    load_lds16(A + (m0 + srow) * 512 + k0 + scol, (char*)As + t * 16);
    for (int p = 0; p < WN / 2; ++p)
      load_lds16(B + (n0 + srow + p * 64) * 512 + k0 + scol,
                 (char*)Bs + t * 16 + p * 4096);
    __syncthreads();
    bf16x8 af[WM], bf[WN];
    for (int i = 0; i < WM; ++i)
      af[i] = *(const bf16x8*)&As[(wm * 16 * WM + i * 16 + r16) * 32 + quad * 8];
    for (int j = 0; j < WN; ++j)
      bf[j] = *(const bf16x8*)&Bs[(wn * 16 * WN + j * 16 + r16) * 32 + quad * 8];
    for (int i = 0; i < WM; ++i)
      for (int j = 0; j < WN; ++j)
        acc[i][j] = __builtin_amdgcn_mfma_f32_16x16x32_bf16(af[i], bf[j], acc[i][j], 0, 0, 0);
  }
  for (int i = 0; i < WM; ++i)
    for (int j = 0; j < WN; ++j) {
      int p_ = n0 + wn * 16 * WN + j * 16 + r16;
      int il = p_ >> 8, jj = p_ & 255;
      long pix = ((long)(r0 + il) << 8) + jj;
      for (int r = 0; r < 4; ++r) {
        int c_ = m0 + wm * 16 * WM + i * 16 + quad * 4 + r;
        long tok = ((long)b << 16) + pix;
        float v = acc[i][j][r] + bf2f(x2[tok * CDIM + c_]);
        out[((long)(b * CDIM + c_) << 16) + pix] = v;
      }
    }
}

// ---------------- K3: MFMA window attention over padded head-plane qkv ----------------
__global__ __launch_bounds__(256) void k3_attn(
    const __hip_bfloat16* __restrict__ qkv,   // chunk planes [sel][head][NTC][32]
    const float* __restrict__ rpb,
    __hip_bfloat16* __restrict__ out,         // full attnout (NTOK,192), shifted-raster
    int wid0) {
  __shared__ alignas(16) short Kp[64 * 32];       // K zero-padded, swz g^=(row>>1)&3
  __shared__ alignas(16) short Vt[32 * 64];       // V^T [dim][tok], swz g^=(dim&7)
  __shared__ alignas(16) short Ps[4][16 * 64];    // per-wave P~ strip, swz g^=(row&7)
  __shared__ float rpbs[225];
  int h = blockIdx.x, widl = blockIdx.y;
  int wid = wid0 + widl;
  int t = threadIdx.x;
  int wv = t >> 6, lane = t & 63, quad = lane >> 4, r16 = lane & 15;
  int wi_l = widl >> 5, wjl = widl & 31;
  const short* qk = (const short*)qkv;
  const short* Qp  = qk + ((long)h << 21);        // h*NTC*32
  const short* Kpg = Qp + (long)NTC * 256;
  const short* Vpg = Qp + (long)NTC * 512;

  if (t < 225) rpbs[t] = rpb[t * NHEADS + h];

  // ---- K staging: [64][32] bf16, cols 24-31 zero ----
  {
    int kr = t >> 2, kq = t & 3;
    bf16x8 kv = {0, 0, 0, 0, 0, 0, 0, 0};
    if (kq < 3) {
      int ltok = ((((wi_l << 3) + (kr >> 3)) << 8) + (wjl << 3) + (kr & 7));
      kv = *(const bf16x8*)(Kpg + ((long)ltok << 5) + kq * 8);
    }
    *(bf16x8*)&Kp[kr * 32 + ((kq ^ ((kr >> 1) & 3)) << 3)] = kv;
  }
  // ---- V staging transposed: Vt[dim][tok]; rows 24-31 zero ----
  {
    int tok = t & 63, q8 = t >> 6;
    if (q8 < 3) {
      int ltok = ((((wi_l << 3) + (tok >> 3)) << 8) + (wjl << 3) + (tok & 7));
      bf16x8 vv = *(const bf16x8*)(Vpg + ((long)ltok << 5) + q8 * 8);
      #pragma unroll
      for (int e = 0; e < 8; ++e) {
        int d = q8 * 8 + e;
        Vt[d * 64 + (((tok >> 3) ^ (d & 7)) << 3) + (tok & 7)] = vv[e];
      }
    } else {
      int zt = t - 192;
      int d = 24 + (zt >> 3), tokg = zt & 7;
      bf16x8 z = {0, 0, 0, 0, 0, 0, 0, 0};
      *(bf16x8*)&Vt[d * 64 + ((tokg ^ (d & 7)) << 3)] = z;
    }
  }
  // ---- Q fragment: quad<3 loads real dims; quad==3 covers pad dims 24-31, which are
  // UNWRITTEN in the padded plane (stale poison could be NaN; NaN*0 != 0) -> zero it.
  bf16x8 qf = {0, 0, 0, 0, 0, 0, 0, 0};
  if (quad < 3) {
    int nn = wv * 16 + r16;
    int ltok = ((((wi_l << 3) + (nn >> 3)) << 8) + (wjl << 3) + (nn & 7));
    qf = *(const bf16x8*)(Qp + ((long)ltok << 5) + quad * 8);
  }
  __syncthreads();

  // ---- S = Q*K^T ----
  floatx4 sj[4];
  int kswz = (quad ^ ((r16 >> 1) & 3)) << 3;
  #pragma unroll
  for (int j = 0; j < 4; ++j) {
    bf16x8 kf = *(const bf16x8*)&Kp[(j * 16 + r16) * 32 + kswz];
    sj[j] = __builtin_amdgcn_mfma_f32_16x16x32_bf16(
        qf, kf, (floatx4){0.f, 0.f, 0.f, 0.f}, 0, 0, 0);
  }

  int b = wid >> 10, wi = (wid >> 5) & 31, wj = wid & 31;
  int rkj[4];
  #pragma unroll
  for (int j = 0; j < 4; ++j) {
    int m = j * 16 + r16;
    int gsi = wi * 8 + (m >> 3), gsj = wj * 8 + (m & 7);
    rkj[j] = ((gsi < 248) ? 0 : (gsi < 252 ? 1 : 2)) * 3 +
             ((gsj < 248) ? 0 : (gsj < 252 ? 1 : 2));
  }

  float rs[4];
  #pragma unroll
  for (int r = 0; r < 4; ++r) {
    int n = wv * 16 + quad * 4 + r;
    int ti = n >> 3, tj = n & 7;
    int gi = wi * 8 + ti, gj = wj * 8 + tj;
    int rq = ((gi < 248) ? 0 : (gi < 252 ? 1 : 2)) * 3 +
             ((gj < 248) ? 0 : (gj < 252 ? 1 : 2));
    float val[4];
    float mx = -1e30f;
    #pragma unroll
    for (int j = 0; j < 4; ++j) {
      int m = j * 16 + r16;
      int idx = (ti - (m >> 3) + 7) * 15 + (tj - (m & 7) + 7);
      float v = sj[j][r] * 0.20412414523193154f + rpbs[idx];
      if (rkj[j] != rq) v -= 100.0f;
      val[j] = v;
      mx = fmaxf(mx, v);
    }
    #pragma unroll
    for (int off = 1; off < 16; off <<= 1) mx = fmaxf(mx, __shfl_xor(mx, off));
    float sum = 0.f;
    int row = quad * 4 + r;
    #pragma unroll
    for (int j = 0; j < 4; ++j) {
      float p = __expf(val[j] - mx);
      sum += p;
      int col = j * 16 + r16;
      Ps[wv][row * 64 + ((((col >> 3) ^ (row & 7)) << 3)) + (col & 7)] = f2s(p);
    }
    #pragma unroll
    for (int off = 1; off < 16; off <<= 1) sum += __shfl_xor(sum, off);
    rs[r] = 1.0f / sum;
  }
  __syncthreads();

  // ---- O = P~ * V^T ----
  floatx4 o0 = {0.f, 0.f, 0.f, 0.f}, o1 = {0.f, 0.f, 0.f, 0.f};
  #pragma unroll
  for (int kk = 0; kk < 2; ++kk) {
    int g = (((kk * 4 + quad) ^ (r16 & 7)) << 3);
    bf16x8 pa = *(const bf16x8*)&Ps[wv][r16 * 64 + g];
    bf16x8 b0 = *(const bf16x8*)&Vt[r16 * 64 + g];
    bf16x8 b1 = *(const bf16x8*)&Vt[(16 + r16) * 64 + g];
    o0 = __builtin_amdgcn_mfma_f32_16x16x32_bf16(pa, b0, o0, 0, 0, 0);
    o1 = __builtin_amdgcn_mfma_f32_16x16x32_bf16(pa, b1, o1, 0, 0, 0);
  }
  #pragma unroll
  for (int r = 0; r < 4; ++r) {
    int n = wv * 16 + quad * 4 + r;
    int gi = wi * 8 + (n >> 3), gj = wj * 8 + (n & 7);
    long ob = (((long)b << 16) + (gi << 8) + gj) * CDIM + h * HD;
    out[ob + r16] = f2bf(o0[r] * rs[r]);
    if (r16 < 8) out[ob + 16 + r16] = f2bf(o1[r] * rs[r]);
  }
}

// ---------------- K4: residual + unshift gather + LN2 stats (parallel-reduce form) -----
__global__ __launch_bounds__(256) void k4_res_raster(
    const float* __restrict__ x,
    const __hip_bfloat16* __restrict__ tmp,   // proj out, shifted-raster order
    __hip_bfloat16* __restrict__ x2,          // unshifted token-major (NTOK,192)
    float* __restrict__ stats) {              // (NTOK,2): mean, rstd
  __shared__ float xs[32][193];
  int bid = blockIdx.x;
  int b = bid >> 11, i = (bid >> 3) & 255, j0 = (bid & 7) << 5;
  int tid = threadIdx.x;
  int lane = tid & 63, wv = tid >> 6;
  int p0 = (lane & 7) << 2;
  int cb = wv * 8 + (lane >> 3);
  long pbase = ((long)(b * CDIM + cb) << 16) + (i << 8) + j0 + p0;
  #pragma unroll
  for (int co = 0; co < 6; ++co) {
    floatx4 v = *(const floatx4*)(x + pbase + ((long)co << 21));
    int c = co * 32 + cb;
    xs[p0 + 0][c] = v[0];
    xs[p0 + 1][c] = v[1];
    xs[p0 + 2][c] = v[2];
    xs[p0 + 3][c] = v[3];
  }
  __syncthreads();
  int p = tid >> 3, q = tid & 7, c0 = q * 24;
  int j = j0 + p;
  int si = (i + 252) & 255, sj = (j + 252) & 255;
  long tsh = ((long)b << 16) + (si << 8) + sj;
  const short* tp = (const short*)tmp + tsh * 192 + c0;
  bf16x8 t0 = *(const bf16x8*)(tp);
  bf16x8 t1 = *(const bf16x8*)(tp + 8);
  bf16x8 t2v = *(const bf16x8*)(tp + 16);
  float v[24], s = 0.f, sq = 0.f;
  #pragma unroll
  for (int e = 0; e < 8; ++e) {
    float a0 = xs[p][c0 + e     ] + s2f(t0[e]);
    float a1 = xs[p][c0 + e + 8 ] + s2f(t1[e]);
    float a2 = xs[p][c0 + e + 16] + s2f(t2v[e]);
    v[e] = a0; v[e + 8] = a1; v[e + 16] = a2;
    s += a0 + a1 + a2;
    sq += a0 * a0 + a1 * a1 + a2 * a2;
  }
  #pragma unroll
  for (int off = 1; off < 8; off <<= 1) { s += __shfl_xor(s, off); sq += __shfl_xor(sq, off); }
  float mean = s * (1.0f / 192.0f);
  float var  = sq * (1.0f / 192.0f) - mean * mean;
  float rstd = rsqrtf(var + 1e-5f);
  long t2g = ((long)b << 16) + (i << 8) + j;
  if (q == 0) { stats[2 * t2g] = mean; stats[2 * t2g + 1] = rstd; }
  unsigned pk[12];
  #pragma unroll
  for (int e = 0; e < 12; ++e) {
    unsigned lo = (unsigned short)f2s(v[2 * e]);
    unsigned hi = (unsigned short)f2s(v[2 * e + 1]);
    pk[e] = lo | (hi << 16);
  }
  char* gout = (char*)x2 + t2g * 384 + q * 48;
  *(uintx4*)(gout     ) = (uintx4){pk[0], pk[1], pk[2], pk[3]};
  *(uintx4*)(gout + 16) = (uintx4){pk[4], pk[5], pk[6], pk[7]};
  *(uintx4*)(gout + 32) = (uintx4){pk[8], pk[9], pk[10], pk[11]};
}

// ---------------- K7v2: depthwise 3x3 + gated exact GELU, vectorized x8 ----------------
__global__ __launch_bounds__(256) void k7_dwgate(
    const __hip_bfloat16* __restrict__ pin,
    const __hip_bfloat16* __restrict__ wa,   // (9,512) tap-major bf16
    const __hip_bfloat16* __restrict__ wg,   // (9,512)
    __hip_bfloat16* __restrict__ out,        // (16384, 512)
    int r0) {
  int t = threadIdx.x;
  int oct = t & 63, pl = t >> 6;
  int p = blockIdx.x * 4 + pl;               // [0, 16384)
  int il = p >> 8, j = p & 255;
  int gi = r0 + il;
  int c0 = oct << 3;
  float a[8], g[8];
  for (int e = 0; e < 8; ++e) { a[e] = 0.f; g[e] = 0.f; }
  for (int di = -1; di <= 1; ++di) {
    int ii = gi + di; if (ii < 0 || ii > 255) continue;
    int br = il + di + 1;                    // [0, 66)
    for (int dj = -1; dj <= 1; ++dj) {
      int jj = j + dj; if (jj < 0 || jj > 255) continue;
      long nbase = ((long)((br << 8) + jj)) << 10;   // *1024
      int tap = (di + 1) * 3 + (dj + 1);
      bf16x8 va  = *(const bf16x8*)((const short*)pin + nbase + c0);
      bf16x8 vg  = *(const bf16x8*)((const short*)pin + nbase + 512 + c0);
      bf16x8 wa8 = *(const bf16x8*)((const short*)wa + tap * 512 + c0);
      bf16x8 wg8 = *(const bf16x8*)((const short*)wg + tap * 512 + c0);
      for (int e = 0; e < 8; ++e) {
        a[e] += s2f(wa8[e]) * s2f(va[e]);
        g[e] += s2f(wg8[e]) * s2f(vg[e]);
      }
    }
  }
  bf16x8 r;
  for (int e = 0; e < 8; ++e) {
    float ge = 0.5f * a[e] * (1.0f + erff(a[e] * 0.70710678118654752f));
    r[e] = f2s(ge * g[e]);
  }
  *(bf16x8*)((short*)out + (long)p * 512 + c0) = r;
}

extern "C" void kernel_launch(void* const* d_in, const int* in_sizes, int n_in,
                              void* d_out, int out_size, void* d_ws, size_t ws_size,
                              hipStream_t stream) {
  const float* x       = (const float*)d_in[0];
  const float* norm1_w = (const float*)d_in[1];
  const float* norm1_b = (const float*)d_in[2];
  const float* qkv_w   = (const float*)d_in[3];
  const float* rpb     = (const float*)d_in[4];
  const float* proj_w  = (const float*)d_in[5];
  const float* proj_b  = (const float*)d_in[6];
  const float* norm2_w = (const float*)d_in[7];
  const float* norm2_b = (const float*)d_in[8];
  const float* pin_w   = (const float*)d_in[9];
  const float* dw_w    = (const float*)d_in[10];
  const float* pout_w  = (const float*)d_in[11];

  // Workspace layout (bytes), peak ~121.5 MB:
  char* ws = (char*)d_ws;
  __hip_bfloat16* wsLN1 = (__hip_bfloat16*)(ws);
  __hip_bfloat16* wsPRJ = (__hip_bfloat16*)(ws);
  __hip_bfloat16* wsPINC= (__hip_bfloat16*)(ws);                  // 16896*1024*2 = 34,603,008
  __hip_bfloat16* wsATT = (__hip_bfloat16*)(ws + 50331648UL);
  __hip_bfloat16* wsX2  = (__hip_bfloat16*)(ws + 50331648UL);
  float*          wsST  = (float*)         (ws + 100663296UL);
  __hip_bfloat16* wsGT  = (__hip_bfloat16*)(ws + 101711872UL);    // 16384*512*2 = 16,777,216
  __hip_bfloat16* wsWA  = (__hip_bfloat16*)(ws + 118489088UL);    // 9*512*2 = 9,216 B
  __hip_bfloat16* wsWG  = (__hip_bfloat16*)(ws + 118507520UL);    // 9,216 B
  float*          wsS   = (float*)         (ws + 118517760UL);    // 4 KB
  float*          wsT   = (float*)         (ws + 118525952UL);    // 4 KB
  __hip_bfloat16* wsPW  = (__hip_bfloat16*)(ws + 120586240UL);    // 192*512
  __hip_bfloat16* wsQW  = (__hip_bfloat16*)(ws + 120782848UL);    // 110592
  __hip_bfloat16* wsPJW = (__hip_bfloat16*)(ws + 121004032UL);    // 36864
  __hip_bfloat16* wsPIW = (__hip_bfloat16*)(ws + 121077760UL);    // 1024*192 = 196608
  float* out = (float*)d_out;
  // d_out (100.66 MB) doubles as padded qkv scratch during the attention phase:
  // [sel][head][NTC][32] bf16 = 65536*768*2 = 100,663,296 B exactly.
  __hip_bfloat16* qkvbuf = (__hip_bfloat16*)d_out;

  // weight conversion / padding / LN2-fold vectors
  kcvt<<<(110592 + 255) / 256, 256, 0, stream>>>(qkv_w, wsQW, 110592);
  kcvt<<<(36864 + 255) / 256, 256, 0, stream>>>(proj_w, wsPJW, 36864);
  k0_padpout<<<384, 256, 0, stream>>>(pout_w, wsPW);
  k0_padpin<<<768, 256, 0, stream>>>(pin_w, norm2_w, wsPIW);
  k0_st<<<4, 256, 0, stream>>>(pin_w, norm2_w, norm2_b, wsS, wsT);
  k0_wtap<<<18, 256, 0, stream>>>(dw_w, wsWA, wsWG);
  // LN1 + shift -> wsLN1 (shifted-raster token-major, 192), coalesced both ways
  k1_ln_raster<<<4096, 256, 0, stream>>>(x, norm1_w, norm1_b, wsLN1);
  // qkv GEMM (padded head-plane scatter) + MFMA attention, 2 chunks of 65536 tokens
  for (int b = 0; b < 2; ++b) {
    gemm_qkv<<<dim3(9, 512), 256, 0, stream>>>(
        wsLN1 + (long)b * 65536 * CDIM, wsQW, qkvbuf);
    k3_attn<<<dim3(8, 1024), 256, 0, stream>>>(qkvbuf, rpb, wsATT, b * 1024);
  }
  // proj GEMM (+bias): shifted-raster order -> wsPRJ
  gemm_lds<4, 2, 1><<<dim3(3, 1024), 256, 0, stream>>>(
      wsATT, wsPJW, proj_b, wsPRJ, 192, 192, 192, 192);
  // residual + unshift + LN2 stats -> wsX2 (token-major), wsST (coalesced)
  k4_res_raster<<<4096, 256, 0, stream>>>(x, wsPRJ, wsX2, wsST);
  // FFN, 8 chunks of 64 image rows (per batch), 1-row halo; LN2 fused into pin GEMM
  for (int cc = 0; cc < 8; ++cc) {
    int b = cc >> 2, r0 = (cc & 3) * 64;
    gemm_pin<<<dim3(8, 132), 256, 0, stream>>>(
        wsX2, wsPIW, wsST, wsS, wsT, wsPINC, b, r0);
    k7_dwgate<<<4096, 256, 0, stream>>>(wsPINC, wsWA, wsWG, wsGT, r0);
    gemm_pout<<<dim3(128, 3), 256, 0, stream>>>(wsPW, wsGT, wsX2, out, b, r0);
  }
}

// Round 7
// 889.954 us; speedup vs baseline: 1.0447x; 1.0447x over previous
//
#include <hip/hip_runtime.h>
#include <hip/hip_bf16.h>
#include <math.h>

#define CDIM 192
#define NTOK 131072   /* B*H*W = 2*256*256 */
#define HD 24
#define NHEADS 8
#define NTC 65536     /* tokens per attention chunk (one batch) */

typedef __attribute__((ext_vector_type(4))) float floatx4;
typedef __attribute__((ext_vector_type(8))) short bf16x8;
typedef __attribute__((ext_vector_type(4))) unsigned int uintx4;

static __device__ __forceinline__ float bf2f(__hip_bfloat16 h) { return __bfloat162float(h); }
static __device__ __forceinline__ __hip_bfloat16 f2bf(float f) { return __float2bfloat16(f); }
static __device__ __forceinline__ float s2f(short s) {
  union { unsigned u; float f; } c; c.u = ((unsigned)(unsigned short)s) << 16; return c.f;
}
static __device__ __forceinline__ short f2s(float f) {
  __hip_bfloat16 h = __float2bfloat16(f);
  union { __hip_bfloat16 h; short s; } c; c.h = h; return c.s;
}
static __device__ __forceinline__ void load_lds16(const void* g, void* l) {
  __builtin_amdgcn_global_load_lds(
      (const __attribute__((address_space(1))) void*)g,
      (__attribute__((address_space(3))) void*)l, 16, 0, 0);
}

// ---------------- KC: f32 -> bf16 convert ----------------
__global__ __launch_bounds__(256) void kcvt(
    const float* __restrict__ in, __hip_bfloat16* __restrict__ out, int n) {
  int i = blockIdx.x * 256 + threadIdx.x;
  if (i < n) out[i] = f2bf(in[i]);
}

// ---------------- K0a: pad pout_w (192,510) f32 -> (192,512) bf16 ----------------
__global__ __launch_bounds__(256) void k0_padpout(
    const float* __restrict__ w, __hip_bfloat16* __restrict__ o) {
  int idx = blockIdx.x * 256 + threadIdx.x;   // 192*512
  int n = idx >> 9, k = idx & 511;
  o[idx] = (k < 510) ? f2bf(w[n * 510 + k]) : f2bf(0.f);
}

// ---------------- K0b: pad pin_w (1020,192) f32 -> (1024,192) bf16, scaled by nw ----
__global__ __launch_bounds__(256) void k0_padpin(
    const float* __restrict__ w, const float* __restrict__ nw,
    __hip_bfloat16* __restrict__ o) {
  int idx = blockIdx.x * 256 + threadIdx.x;   // 1024*192
  int n = idx / 192, k = idx % 192;
  int src = (n < 510) ? n : ((n >= 512 && n < 1022) ? n - 2 : -1);
  o[idx] = (src >= 0) ? f2bf(w[src * 192 + k] * nw[k]) : f2bf(0.f);
}

// ---------------- K0s: LN2-fold vectors S[n]=sum(W*nw), T[n]=sum(W*nb) ----------------
__global__ __launch_bounds__(256) void k0_st(
    const float* __restrict__ w, const float* __restrict__ nw,
    const float* __restrict__ nb, float* __restrict__ S, float* __restrict__ T) {
  int n = blockIdx.x * 256 + threadIdx.x;     // [0,1024)
  int src = (n < 510) ? n : ((n >= 512 && n < 1022) ? n - 2 : -1);
  float s = 0.f, t = 0.f;
  if (src >= 0)
    for (int c = 0; c < 192; ++c) {
      float v = w[src * 192 + c];
      s += v * nw[c]; t += v * nb[c];
    }
  S[n] = s; T[n] = t;
}

// ---------------- K0c: transpose dw_w (1020,9) f32 -> tap-major bf16 WA[9][512], WG[9][512] ---
__global__ __launch_bounds__(256) void k0_wtap(
    const float* __restrict__ wdw, __hip_bfloat16* __restrict__ wa,
    __hip_bfloat16* __restrict__ wg) {
  int idx = blockIdx.x * 256 + threadIdx.x;   // 9*512
  if (idx >= 9 * 512) return;
  int tap = idx >> 9, c = idx & 511;
  wa[idx] = (c < 510) ? f2bf(wdw[c * 9 + tap]) : f2bf(0.f);
  wg[idx] = (c < 510) ? f2bf(wdw[(c + 510) * 9 + tap]) : f2bf(0.f);
}

// ---------------- K1: LN1 + cyclic shift, shifted-raster order (f32 in, bf16 out) --------
__global__ __launch_bounds__(256) void k1_ln_raster(
    const float* __restrict__ x,
    const float* __restrict__ w,
    const float* __restrict__ bsh,
    __hip_bfloat16* __restrict__ out) {
  __shared__ float xs[32][193];
  __shared__ float wls[192], bls[192];
  int bid = blockIdx.x;
  int b = bid >> 11, si = (bid >> 3) & 255, sj0 = (bid & 7) << 5;
  int i = (si + 4) & 255;                     // unshifted source row
  int tid = threadIdx.x;
  int lane = tid & 63, wv = tid >> 6;
  if (tid < 192) { wls[tid] = w[tid]; bls[tid] = bsh[tid]; }
  int p0 = (lane & 7) << 2;
  int cb = wv * 8 + (lane >> 3);
  int j4 = (sj0 + p0 + 4) & 255;              // wrap-aligned source column
  long pbase = ((long)(b * CDIM + cb) << 16) + (i << 8) + j4;
  #pragma unroll
  for (int co = 0; co < 6; ++co) {
    floatx4 v = *(const floatx4*)(x + pbase + ((long)co << 21));
    int c = co * 32 + cb;
    xs[p0 + 0][c] = v[0];
    xs[p0 + 1][c] = v[1];
    xs[p0 + 2][c] = v[2];
    xs[p0 + 3][c] = v[3];
  }
  __syncthreads();
  int p = tid >> 3, q = tid & 7, c0 = q * 24;
  float v[24], s = 0.f, sq = 0.f;
  #pragma unroll
  for (int e = 0; e < 24; ++e) {
    float t = xs[p][c0 + e]; v[e] = t; s += t; sq += t * t;
  }
  #pragma unroll
  for (int off = 1; off < 8; off <<= 1) { s += __shfl_xor(s, off); sq += __shfl_xor(sq, off); }
  float mean = s * (1.0f / 192.0f);
  float var  = sq * (1.0f / 192.0f) - mean * mean;
  float rstd = rsqrtf(var + 1e-5f);
  unsigned pk[12];
  #pragma unroll
  for (int e = 0; e < 12; ++e) {
    unsigned lo = (unsigned short)f2s((v[2*e  ] - mean) * rstd * wls[c0 + 2*e  ] + bls[c0 + 2*e  ]);
    unsigned hi = (unsigned short)f2s((v[2*e+1] - mean) * rstd * wls[c0 + 2*e+1] + bls[c0 + 2*e+1]);
    pk[e] = lo | (hi << 16);
  }
  long tok0 = ((long)b << 16) + (si << 8) + sj0;
  char* gout = (char*)out + (tok0 + p) * 384 + q * 48;
  *(uintx4*)(gout     ) = (uintx4){pk[0], pk[1], pk[2], pk[3]};
  *(uintx4*)(gout + 16) = (uintx4){pk[4], pk[5], pk[6], pk[7]};
  *(uintx4*)(gout + 32) = (uintx4){pk[8], pk[9], pk[10], pk[11]};
}

// ---------------- LDS-staged MFMA GEMM: C(M,N) = A(M,K)*B(N,K)^T ----------------
// With BN=64, each block's col range = 128 B of a C row -> sector-exact stores (no RMW).
template <int WM, int WN, int EPI>
__global__ __launch_bounds__(256) void gemm_lds(
    const __hip_bfloat16* __restrict__ A,
    const __hip_bfloat16* __restrict__ B,
    const float* __restrict__ bias,
    __hip_bfloat16* __restrict__ C,
    int K, int lda, int ldb, int ldc) {
  constexpr int BM = 32 * WM, BN = 32 * WN;
  __shared__ __hip_bfloat16 As[BM * 32];
  __shared__ __hip_bfloat16 Bs[BN * 32];
  int t = threadIdx.x;
  int wave = t >> 6, lane = t & 63;
  int wm = wave >> 1, wn = wave & 1;
  int r16 = lane & 15, quad = lane >> 4;
  long m0 = (long)blockIdx.y * BM;
  long n0 = (long)blockIdx.x * BN;
  int srow = t >> 2, scol = (t & 3) << 3;
  floatx4 acc[WM][WN];
  for (int i = 0; i < WM; ++i)
    for (int j = 0; j < WN; ++j)
      acc[i][j] = (floatx4){0.f, 0.f, 0.f, 0.f};
  for (int k0 = 0; k0 < K; k0 += 32) {
    __syncthreads();
    for (int p = 0; p < WM / 2; ++p)
      load_lds16(A + (m0 + srow + p * 64) * lda + k0 + scol,
                 (char*)As + t * 16 + p * 4096);
    for (int p = 0; p < WN / 2; ++p)
      load_lds16(B + (n0 + srow + p * 64) * ldb + k0 + scol,
                 (char*)Bs + t * 16 + p * 4096);
    __syncthreads();
    bf16x8 af[WM], bf[WN];
    for (int i = 0; i < WM; ++i)
      af[i] = *(const bf16x8*)&As[(wm * 16 * WM + i * 16 + r16) * 32 + quad * 8];
    for (int j = 0; j < WN; ++j)
      bf[j] = *(const bf16x8*)&Bs[(wn * 16 * WN + j * 16 + r16) * 32 + quad * 8];
    for (int i = 0; i < WM; ++i)
      for (int j = 0; j < WN; ++j)
        acc[i][j] = __builtin_amdgcn_mfma_f32_16x16x32_bf16(af[i], bf[j], acc[i][j], 0, 0, 0);
  }
  for (int i = 0; i < WM; ++i)
    for (int j = 0; j < WN; ++j) {
      int col = n0 + wn * 16 * WN + j * 16 + r16;
      float badd = (EPI == 1) ? bias[col] : 0.f;
      for (int r = 0; r < 4; ++r) {
        long row = m0 + wm * 16 * WM + i * 16 + quad * 4 + r;
        C[row * ldc + col] = f2bf(acc[i][j][r] + badd);
      }
    }
}

// ---------------- pin GEMM with fused LN2 (A = x2 raw; epilogue applies LN fold) -----
__global__ __launch_bounds__(256) void gemm_pin(
    const __hip_bfloat16* __restrict__ x2,   // (NTOK,192) token-major
    const __hip_bfloat16* __restrict__ B,    // (1024,192) nw-scaled padded pin_w
    const float* __restrict__ stats,         // (NTOK,2)
    const float* __restrict__ Sv,
    const float* __restrict__ Tv,
    __hip_bfloat16* __restrict__ C,          // (16896,1024)
    int bb, int r0) {
  constexpr int WM = 4, WN = 4, BM = 128, BN = 128;
  __shared__ __hip_bfloat16 As[BM * 32];
  __shared__ __hip_bfloat16 Bs[BN * 32];
  int t = threadIdx.x;
  int wave = t >> 6, lane = t & 63;
  int wm = wave >> 1, wn = wave & 1;
  int r16 = lane & 15, quad = lane >> 4;
  int m0 = blockIdx.y * BM;
  int n0 = blockIdx.x * BN;
  int srow = t >> 2, scol = (t & 3) << 3;
  floatx4 acc[WM][WN];
  for (int i = 0; i < WM; ++i)
    for (int j = 0; j < WN; ++j)
      acc[i][j] = (floatx4){0.f, 0.f, 0.f, 0.f};
  for (int k0 = 0; k0 < 192; k0 += 32) {
    __syncthreads();
    for (int p = 0; p < 2; ++p) {
      int rr = m0 + srow + p * 64;
      int il = rr >> 8, jj = rr & 255;
      int gi = r0 - 1 + il; gi = gi < 0 ? 0 : (gi > 255 ? 255 : gi);
      long tok = ((long)bb << 16) + (gi << 8) + jj;
      load_lds16(x2 + tok * 192 + k0 + scol, (char*)As + t * 16 + p * 4096);
    }
    for (int p = 0; p < 2; ++p)
      load_lds16(B + (n0 + srow + p * 64) * 192 + k0 + scol,
                 (char*)Bs + t * 16 + p * 4096);
    __syncthreads();
    bf16x8 af[WM], bf[WN];
    for (int i = 0; i < WM; ++i)
      af[i] = *(const bf16x8*)&As[(wm * 64 + i * 16 + r16) * 32 + quad * 8];
    for (int j = 0; j < WN; ++j)
      bf[j] = *(const bf16x8*)&Bs[(wn * 64 + j * 16 + r16) * 32 + quad * 8];
    for (int i = 0; i < WM; ++i)
      for (int j = 0; j < WN; ++j)
        acc[i][j] = __builtin_amdgcn_mfma_f32_16x16x32_bf16(af[i], bf[j], acc[i][j], 0, 0, 0);
  }
  for (int i = 0; i < WM; ++i) {
    float mr[4], rsd[4];
    #pragma unroll
    for (int r = 0; r < 4; ++r) {
      int row = m0 + wm * 64 + i * 16 + quad * 4 + r;
      int il = row >> 8, jj = row & 255;
      int gi = r0 - 1 + il; gi = gi < 0 ? 0 : (gi > 255 ? 255 : gi);
      long tok = ((long)bb << 16) + (gi << 8) + jj;
      mr[r] = stats[2 * tok]; rsd[r] = stats[2 * tok + 1];
    }
    for (int j = 0; j < WN; ++j) {
      int col = n0 + wn * 64 + j * 16 + r16;
      float sv = Sv[col], tv = Tv[col];
      for (int r = 0; r < 4; ++r) {
        int row = m0 + wm * 64 + i * 16 + quad * 4 + r;
        C[(long)row * 1024 + col] = f2bf(acc[i][j][r] * rsd[r] - mr[r] * rsd[r] * sv + tv);
      }
    }
  }
}

// ---------------- pout GEMM (transposed output) + residual + coalesced f32 store ----
__global__ __launch_bounds__(256) void gemm_pout(
    const __hip_bfloat16* __restrict__ A,    // padded pout_w (192,512)
    const __hip_bfloat16* __restrict__ B,    // gated chunk (16384,512)
    const __hip_bfloat16* __restrict__ x2,
    float* __restrict__ out,
    int b, int r0) {
  constexpr int WM = 2, WN = 4, BM = 64, BN = 128;
  __shared__ __hip_bfloat16 As[BM * 32];
  __shared__ __hip_bfloat16 Bs[BN * 32];
  int t = threadIdx.x;
  int wave = t >> 6, lane = t & 63;
  int wm = wave >> 1, wn = wave & 1;
  int r16 = lane & 15, quad = lane >> 4;
  long m0 = (long)blockIdx.y * BM;
  long n0 = (long)blockIdx.x * BN;
  int srow = t >> 2, scol = (t & 3) << 3;
  floatx4 acc[WM][WN];
  for (int i = 0; i < WM; ++i)
    for (int j = 0; j < WN; ++j)
      acc[i][j] = (floatx4){0.f, 0.f, 0.f, 0.f};
  for (int k0 = 0; k0 < 512; k0 += 32) {
    __syncthreads();
    load_lds16(A + (m0 + srow) * 512 + k0 + scol, (char*)As + t * 16);
    for (int p = 0; p < WN / 2; ++p)
      load_lds16(B + (n0 + srow + p * 64) * 512 + k0 + scol,
                 (char*)Bs + t * 16 + p * 4096);
    __syncthreads();
    bf16x8 af[WM], bf[WN];
    for (int i = 0; i < WM; ++i)
      af[i] = *(const bf16x8*)&As[(wm * 16 * WM + i * 16 + r16) * 32 + quad * 8];
    for (int j = 0; j < WN; ++j)
      bf[j] = *(const bf16x8*)&Bs[(wn * 16 * WN + j * 16 + r16) * 32 + quad * 8];
    for (int i = 0; i < WM; ++i)
      for (int j = 0; j < WN; ++j)
        acc[i][j] = __builtin_amdgcn_mfma_f32_16x16x32_bf16(af[i], bf[j], acc[i][j], 0, 0, 0);
  }
  for (int i = 0; i < WM; ++i)
    for (int j = 0; j < WN; ++j) {
      int p_ = n0 + wn * 16 * WN + j * 16 + r16;
      int il = p_ >> 8, jj = p_ & 255;
      long pix = ((long)(r0 + il) << 8) + jj;
      for (int r = 0; r < 4; ++r) {
        int c_ = m0 + wm * 16 * WM + i * 16 + quad * 4 + r;
        long tok = ((long)b << 16) + pix;
        float v = acc[i][j][r] + bf2f(x2[tok * CDIM + c_]);
        out[((long)(b * CDIM + c_) << 16) + pix] = v;
      }
    }
}

// ---------------- K3: MFMA window attention over row-major qkv (stride 576) ----------
// 1D grid 8192 per chunk, decode wgid = g*64 + h*8 + r -> widl = g*8+r, head = h:
// all 8 head-blocks of a window share wgid%8 (same XCD under round-robin) AND are
// adjacent in that XCD's dispatch order -> the window's 73.7 KB of qkv rows are read
// once from HBM and 8x from L2.
__global__ __launch_bounds__(256) void k3_attn(
    const __hip_bfloat16* __restrict__ qkv,   // chunk base, stride 576, NTC tokens
    const float* __restrict__ rpb,
    __hip_bfloat16* __restrict__ out,         // full attnout (NTOK,192), shifted-raster
    int wid0) {
  __shared__ alignas(16) short Kp[64 * 32];       // K zero-padded, swz g^=(row>>1)&3
  __shared__ alignas(16) short Vt[32 * 64];       // V^T [dim][tok], swz g^=(dim&7)
  __shared__ alignas(16) short Ps[4][16 * 64];    // per-wave P~ strip, swz g^=(row&7)
  __shared__ float rpbs[225];
  int bidx = blockIdx.x;
  int h = (bidx >> 3) & 7;
  int widl = ((bidx >> 6) << 3) | (bidx & 7);     // [0,1024)
  int wid = wid0 + widl;
  int t = threadIdx.x;
  int wv = t >> 6, lane = t & 63, quad = lane >> 4, r16 = lane & 15;
  int wi_l = widl >> 5, wjl = widl & 31;
  const short* qk = (const short*)qkv;

  if (t < 225) rpbs[t] = rpb[t * NHEADS + h];

  // ---- K staging: [64][32] bf16, cols 24-31 zero ----
  {
    int kr = t >> 2, kq = t & 3;
    bf16x8 kv = {0, 0, 0, 0, 0, 0, 0, 0};
    if (kq < 3) {
      long ltok = (long)((((wi_l << 3) + (kr >> 3)) << 8) + (wjl << 3) + (kr & 7));
      kv = *(const bf16x8*)(qk + ltok * 576 + 192 + h * HD + kq * 8);
    }
    *(bf16x8*)&Kp[kr * 32 + ((kq ^ ((kr >> 1) & 3)) << 3)] = kv;
  }
  // ---- V staging transposed: Vt[dim][tok]; rows 24-31 zero ----
  {
    int tok = t & 63, q8 = t >> 6;
    if (q8 < 3) {
      long ltok = (long)((((wi_l << 3) + (tok >> 3)) << 8) + (wjl << 3) + (tok & 7));
      bf16x8 vv = *(const bf16x8*)(qk + ltok * 576 + 384 + h * HD + q8 * 8);
      #pragma unroll
      for (int e = 0; e < 8; ++e) {
        int d = q8 * 8 + e;
        Vt[d * 64 + (((tok >> 3) ^ (d & 7)) << 3) + (tok & 7)] = vv[e];
      }
    } else {
      int zt = t - 192;
      int d = 24 + (zt >> 3), tokg = zt & 7;
      bf16x8 z = {0, 0, 0, 0, 0, 0, 0, 0};
      *(bf16x8*)&Vt[d * 64 + ((tokg ^ (d & 7)) << 3)] = z;
    }
  }
  // ---- Q fragment: quad<3 real dims; quad==3 zeroed (h=7 last token would read
  // past the chunk into poison; K-zeros don't annihilate NaN) ----
  bf16x8 qf = {0, 0, 0, 0, 0, 0, 0, 0};
  if (quad < 3) {
    int nn = wv * 16 + r16;
    long ltok = (long)((((wi_l << 3) + (nn >> 3)) << 8) + (wjl << 3) + (nn & 7));
    qf = *(const bf16x8*)(qk + ltok * 576 + h * HD + quad * 8);
  }
  __syncthreads();

  // ---- S = Q*K^T ----
  floatx4 sj[4];
  int kswz = (quad ^ ((r16 >> 1) & 3)) << 3;
  #pragma unroll
  for (int j = 0; j < 4; ++j) {
    bf16x8 kf = *(const bf16x8*)&Kp[(j * 16 + r16) * 32 + kswz];
    sj[j] = __builtin_amdgcn_mfma_f32_16x16x32_bf16(
        qf, kf, (floatx4){0.f, 0.f, 0.f, 0.f}, 0, 0, 0);
  }

  int b = wid >> 10, wi = (wid >> 5) & 31, wj = wid & 31;
  int rkj[4];
  #pragma unroll
  for (int j = 0; j < 4; ++j) {
    int m = j * 16 + r16;
    int gsi = wi * 8 + (m >> 3), gsj = wj * 8 + (m & 7);
    rkj[j] = ((gsi < 248) ? 0 : (gsi < 252 ? 1 : 2)) * 3 +
             ((gsj < 248) ? 0 : (gsj < 252 ? 1 : 2));
  }

  float rs[4];
  #pragma unroll
  for (int r = 0; r < 4; ++r) {
    int n = wv * 16 + quad * 4 + r;
    int ti = n >> 3, tj = n & 7;
    int gi = wi * 8 + ti, gj = wj * 8 + tj;
    int rq = ((gi < 248) ? 0 : (gi < 252 ? 1 : 2)) * 3 +
             ((gj < 248) ? 0 : (gj < 252 ? 1 : 2));
    float val[4];
    float mx = -1e30f;
    #pragma unroll
    for (int j = 0; j < 4; ++j) {
      int m = j * 16 + r16;
      int idx = (ti - (m >> 3) + 7) * 15 + (tj - (m & 7) + 7);
      float v = sj[j][r] * 0.20412414523193154f + rpbs[idx];
      if (rkj[j] != rq) v -= 100.0f;
      val[j] = v;
      mx = fmaxf(mx, v);
    }
    #pragma unroll
    for (int off = 1; off < 16; off <<= 1) mx = fmaxf(mx, __shfl_xor(mx, off));
    float sum = 0.f;
    int row = quad * 4 + r;
    #pragma unroll
    for (int j = 0; j < 4; ++j) {
      float p = __expf(val[j] - mx);
      sum += p;
      int col = j * 16 + r16;
      Ps[wv][row * 64 + ((((col >> 3) ^ (row & 7)) << 3)) + (col & 7)] = f2s(p);
    }
    #pragma unroll
    for (int off = 1; off < 16; off <<= 1) sum += __shfl_xor(sum, off);
    rs[r] = 1.0f / sum;
  }
  __syncthreads();

  // ---- O = P~ * V^T ----
  floatx4 o0 = {0.f, 0.f, 0.f, 0.f}, o1 = {0.f, 0.f, 0.f, 0.f};
  #pragma unroll
  for (int kk = 0; kk < 2; ++kk) {
    int g = (((kk * 4 + quad) ^ (r16 & 7)) << 3);
    bf16x8 pa = *(const bf16x8*)&Ps[wv][r16 * 64 + g];
    bf16x8 b0 = *(const bf16x8*)&Vt[r16 * 64 + g];
    bf16x8 b1 = *(const bf16x8*)&Vt[(16 + r16) * 64 + g];
    o0 = __builtin_amdgcn_mfma_f32_16x16x32_bf16(pa, b0, o0, 0, 0, 0);
    o1 = __builtin_amdgcn_mfma_f32_16x16x32_bf16(pa, b1, o1, 0, 0, 0);
  }
  #pragma unroll
  for (int r = 0; r < 4; ++r) {
    int n = wv * 16 + quad * 4 + r;
    int gi = wi * 8 + (n >> 3), gj = wj * 8 + (n & 7);
    long ob = (((long)b << 16) + (gi << 8) + gj) * CDIM + h * HD;
    out[ob + r16] = f2bf(o0[r] * rs[r]);
    if (r16 < 8) out[ob + 16 + r16] = f2bf(o1[r] * rs[r]);
  }
}

// ---------------- K4: residual + unshift gather + LN2 stats (parallel-reduce form) -----
__global__ __launch_bounds__(256) void k4_res_raster(
    const float* __restrict__ x,
    const __hip_bfloat16* __restrict__ tmp,   // proj out, shifted-raster order
    __hip_bfloat16* __restrict__ x2,          // unshifted token-major (NTOK,192)
    float* __restrict__ stats) {              // (NTOK,2): mean, rstd
  __shared__ float xs[32][193];
  int bid = blockIdx.x;
  int b = bid >> 11, i = (bid >> 3) & 255, j0 = (bid & 7) << 5;
  int tid = threadIdx.x;
  int lane = tid & 63, wv = tid >> 6;
  int p0 = (lane & 7) << 2;
  int cb = wv * 8 + (lane >> 3);
  long pbase = ((long)(b * CDIM + cb) << 16) + (i << 8) + j0 + p0;
  #pragma unroll
  for (int co = 0; co < 6; ++co) {
    floatx4 v = *(const floatx4*)(x + pbase + ((long)co << 21));
    int c = co * 32 + cb;
    xs[p0 + 0][c] = v[0];
    xs[p0 + 1][c] = v[1];
    xs[p0 + 2][c] = v[2];
    xs[p0 + 3][c] = v[3];
  }
  __syncthreads();
  int p = tid >> 3, q = tid & 7, c0 = q * 24;
  int j = j0 + p;
  int si = (i + 252) & 255, sj = (j + 252) & 255;
  long tsh = ((long)b << 16) + (si << 8) + sj;
  const short* tp = (const short*)tmp + tsh * 192 + c0;
  bf16x8 t0 = *(const bf16x8*)(tp);
  bf16x8 t1 = *(const bf16x8*)(tp + 8);
  bf16x8 t2v = *(const bf16x8*)(tp + 16);
  float v[24], s = 0.f, sq = 0.f;
  #pragma unroll
  for (int e = 0; e < 8; ++e) {
    float a0 = xs[p][c0 + e     ] + s2f(t0[e]);
    float a1 = xs[p][c0 + e + 8 ] + s2f(t1[e]);
    float a2 = xs[p][c0 + e + 16] + s2f(t2v[e]);
    v[e] = a0; v[e + 8] = a1; v[e + 16] = a2;
    s += a0 + a1 + a2;
    sq += a0 * a0 + a1 * a1 + a2 * a2;
  }
  #pragma unroll
  for (int off = 1; off < 8; off <<= 1) { s += __shfl_xor(s, off); sq += __shfl_xor(sq, off); }
  float mean = s * (1.0f / 192.0f);
  float var  = sq * (1.0f / 192.0f) - mean * mean;
  float rstd = rsqrtf(var + 1e-5f);
  long t2g = ((long)b << 16) + (i << 8) + j;
  if (q == 0) { stats[2 * t2g] = mean; stats[2 * t2g + 1] = rstd; }
  unsigned pk[12];
  #pragma unroll
  for (int e = 0; e < 12; ++e) {
    unsigned lo = (unsigned short)f2s(v[2 * e]);
    unsigned hi = (unsigned short)f2s(v[2 * e + 1]);
    pk[e] = lo | (hi << 16);
  }
  char* gout = (char*)x2 + t2g * 384 + q * 48;
  *(uintx4*)(gout     ) = (uintx4){pk[0], pk[1], pk[2], pk[3]};
  *(uintx4*)(gout + 16) = (uintx4){pk[4], pk[5], pk[6], pk[7]};
  *(uintx4*)(gout + 32) = (uintx4){pk[8], pk[9], pk[10], pk[11]};
}

// ---------------- K7v2: depthwise 3x3 + gated exact GELU, vectorized x8 ----------------
__global__ __launch_bounds__(256) void k7_dwgate(
    const __hip_bfloat16* __restrict__ pin,
    const __hip_bfloat16* __restrict__ wa,   // (9,512) tap-major bf16
    const __hip_bfloat16* __restrict__ wg,   // (9,512)
    __hip_bfloat16* __restrict__ out,        // (16384, 512)
    int r0) {
  int t = threadIdx.x;
  int oct = t & 63, pl = t >> 6;
  int p = blockIdx.x * 4 + pl;               // [0, 16384)
  int il = p >> 8, j = p & 255;
  int gi = r0 + il;
  int c0 = oct << 3;
  float a[8], g[8];
  for (int e = 0; e < 8; ++e) { a[e] = 0.f; g[e] = 0.f; }
  for (int di = -1; di <= 1; ++di) {
    int ii = gi + di; if (ii < 0 || ii > 255) continue;
    int br = il + di + 1;                    // [0, 66)
    for (int dj = -1; dj <= 1; ++dj) {
      int jj = j + dj; if (jj < 0 || jj > 255) continue;
      long nbase = ((long)((br << 8) + jj)) << 10;   // *1024
      int tap = (di + 1) * 3 + (dj + 1);
      bf16x8 va  = *(const bf16x8*)((const short*)pin + nbase + c0);
      bf16x8 vg  = *(const bf16x8*)((const short*)pin + nbase + 512 + c0);
      bf16x8 wa8 = *(const bf16x8*)((const short*)wa + tap * 512 + c0);
      bf16x8 wg8 = *(const bf16x8*)((const short*)wg + tap * 512 + c0);
      for (int e = 0; e < 8; ++e) {
        a[e] += s2f(wa8[e]) * s2f(va[e]);
        g[e] += s2f(wg8[e]) * s2f(vg[e]);
      }
    }
  }
  bf16x8 r;
  for (int e = 0; e < 8; ++e) {
    float ge = 0.5f * a[e] * (1.0f + erff(a[e] * 0.70710678118654752f));
    r[e] = f2s(ge * g[e]);
  }
  *(bf16x8*)((short*)out + (long)p * 512 + c0) = r;
}

extern "C" void kernel_launch(void* const* d_in, const int* in_sizes, int n_in,
                              void* d_out, int out_size, void* d_ws, size_t ws_size,
                              hipStream_t stream) {
  const float* x       = (const float*)d_in[0];
  const float* norm1_w = (const float*)d_in[1];
  const float* norm1_b = (const float*)d_in[2];
  const float* qkv_w   = (const float*)d_in[3];
  const float* rpb     = (const float*)d_in[4];
  const float* proj_w  = (const float*)d_in[5];
  const float* proj_b  = (const float*)d_in[6];
  const float* norm2_w = (const float*)d_in[7];
  const float* norm2_b = (const float*)d_in[8];
  const float* pin_w   = (const float*)d_in[9];
  const float* dw_w    = (const float*)d_in[10];
  const float* pout_w  = (const float*)d_in[11];

  // Workspace layout (bytes), peak ~121.5 MB:
  char* ws = (char*)d_ws;
  __hip_bfloat16* wsLN1 = (__hip_bfloat16*)(ws);
  __hip_bfloat16* wsPRJ = (__hip_bfloat16*)(ws);
  __hip_bfloat16* wsPINC= (__hip_bfloat16*)(ws);                  // 16896*1024*2 = 34,603,008
  __hip_bfloat16* wsATT = (__hip_bfloat16*)(ws + 50331648UL);
  __hip_bfloat16* wsX2  = (__hip_bfloat16*)(ws + 50331648UL);
  float*          wsST  = (float*)         (ws + 100663296UL);
  __hip_bfloat16* wsGT  = (__hip_bfloat16*)(ws + 101711872UL);    // 16384*512*2 = 16,777,216
  __hip_bfloat16* wsWA  = (__hip_bfloat16*)(ws + 118489088UL);    // 9*512*2 = 9,216 B
  __hip_bfloat16* wsWG  = (__hip_bfloat16*)(ws + 118507520UL);    // 9,216 B
  float*          wsS   = (float*)         (ws + 118517760UL);    // 4 KB
  float*          wsT   = (float*)         (ws + 118525952UL);    // 4 KB
  __hip_bfloat16* wsPW  = (__hip_bfloat16*)(ws + 120586240UL);    // 192*512
  __hip_bfloat16* wsQW  = (__hip_bfloat16*)(ws + 120782848UL);    // 110592
  __hip_bfloat16* wsPJW = (__hip_bfloat16*)(ws + 121004032UL);    // 36864
  __hip_bfloat16* wsPIW = (__hip_bfloat16*)(ws + 121077760UL);    // 1024*192 = 196608
  float* out = (float*)d_out;
  // d_out (100.66 MB) doubles as qkv scratch during the attention phase:
  // row-major (NTC,576) bf16 = 75,497,472 B.
  __hip_bfloat16* qkvbuf = (__hip_bfloat16*)d_out;

  // weight conversion / padding / LN2-fold vectors
  kcvt<<<(110592 + 255) / 256, 256, 0, stream>>>(qkv_w, wsQW, 110592);
  kcvt<<<(36864 + 255) / 256, 256, 0, stream>>>(proj_w, wsPJW, 36864);
  k0_padpout<<<384, 256, 0, stream>>>(pout_w, wsPW);
  k0_padpin<<<768, 256, 0, stream>>>(pin_w, norm2_w, wsPIW);
  k0_st<<<4, 256, 0, stream>>>(pin_w, norm2_w, norm2_b, wsS, wsT);
  k0_wtap<<<18, 256, 0, stream>>>(dw_w, wsWA, wsWG);
  // LN1 + shift -> wsLN1 (shifted-raster token-major, 192), coalesced both ways
  k1_ln_raster<<<4096, 256, 0, stream>>>(x, norm1_w, norm1_b, wsLN1);
  // qkv GEMM (row-major, sector-exact stores) + MFMA attention, 2 chunks of 65536 tokens
  for (int b = 0; b < 2; ++b) {
    gemm_lds<4, 2, 0><<<dim3(9, 512), 256, 0, stream>>>(
        wsLN1 + (long)b * 65536 * CDIM, wsQW, nullptr, qkvbuf, 192, 192, 192, 576);
    k3_attn<<<8192, 256, 0, stream>>>(qkvbuf, rpb, wsATT, b * 1024);
  }
  // proj GEMM (+bias): shifted-raster order -> wsPRJ
  gemm_lds<4, 2, 1><<<dim3(3, 1024), 256, 0, stream>>>(
      wsATT, wsPJW, proj_b, wsPRJ, 192, 192, 192, 192);
  // residual + unshift + LN2 stats -> wsX2 (token-major), wsST (coalesced)
  k4_res_raster<<<4096, 256, 0, stream>>>(x, wsPRJ, wsX2, wsST);
  // FFN, 8 chunks of 64 image rows (per batch), 1-row halo; LN2 fused into pin GEMM
  for (int cc = 0; cc < 8; ++cc) {
    int b = cc >> 2, r0 = (cc & 3) * 64;
    gemm_pin<<<dim3(8, 132), 256, 0, stream>>>(
        wsX2, wsPIW, wsST, wsS, wsT, wsPINC, b, r0);
    k7_dwgate<<<4096, 256, 0, stream>>>(wsPINC, wsWA, wsWG, wsGT, r0);
    gemm_pout<<<dim3(128, 3), 256, 0, stream>>>(wsPW, wsGT, wsX2, out, b, r0);
  }
}